// Round 1
// baseline (4850.842 us; speedup 1.0000x reference)
//
#include <hip/hip_runtime.h>
#include <hip/hip_bf16.h>
#include <cstdint>

#define B_ 2
#define N_ 2048
#define H_ 16
#define HID_ 2048
#define QR_ 1536
#define KVR_ 512
#define DN_ 128
#define DR_ 64
#define DV_ 128
#define QHD_ 192

// ---------------------------------------------------------------------------
// Tiled fp32 GEMM: C[M,N] = A[M,K] @ B[K,N].  64x64 tile, BK=16, 4x4 microtile.
// All M,N multiples of 64 and K multiples of 16 in this problem.
// LDS stride 68 (= 17*4) keeps ds_read_b128 16B-aligned and 2-way max on banks.
// ---------------------------------------------------------------------------
__global__ __launch_bounds__(256) void gemm_f32_kernel(
    const float* __restrict__ A, const float* __restrict__ B,
    float* __restrict__ C, int M, int N, int K) {
  __shared__ float As[16][68];
  __shared__ float Bs[16][68];
  const int tid = threadIdx.x;
  const int bm = blockIdx.y << 6;
  const int bn = blockIdx.x << 6;
  const int ty = tid >> 4;          // 0..15 -> row group
  const int tx = tid & 15;          // 0..15 -> col group
  const int la_r = tid >> 2;        // 0..63 A-tile row
  const int la_c = (tid & 3) << 2;  // 0,4,8,12 A-tile k
  const int lb_r = tid >> 4;        // 0..15 B-tile k
  const int lb_c = (tid & 15) << 2; // B-tile col
  const float* Aptr = A + (size_t)(bm + la_r) * K + la_c;
  const float* Bptr = B + (size_t)lb_r * N + bn + lb_c;
  float acc[4][4] = {{0.f, 0.f, 0.f, 0.f}};
  for (int kt = 0; kt < K; kt += 16) {
    float4 av = *(const float4*)(Aptr + kt);
    float4 bv = *(const float4*)(Bptr + (size_t)kt * N);
    As[la_c + 0][la_r] = av.x;
    As[la_c + 1][la_r] = av.y;
    As[la_c + 2][la_r] = av.z;
    As[la_c + 3][la_r] = av.w;
    *(float4*)&Bs[lb_r][lb_c] = bv;
    __syncthreads();
#pragma unroll
    for (int k = 0; k < 16; ++k) {
      float4 a = *(const float4*)&As[k][ty << 2];
      float4 b = *(const float4*)&Bs[k][tx << 2];
      acc[0][0] += a.x * b.x; acc[0][1] += a.x * b.y; acc[0][2] += a.x * b.z; acc[0][3] += a.x * b.w;
      acc[1][0] += a.y * b.x; acc[1][1] += a.y * b.y; acc[1][2] += a.y * b.z; acc[1][3] += a.y * b.w;
      acc[2][0] += a.z * b.x; acc[2][1] += a.z * b.y; acc[2][2] += a.z * b.z; acc[2][3] += a.z * b.w;
      acc[3][0] += a.w * b.x; acc[3][1] += a.w * b.y; acc[3][2] += a.w * b.z; acc[3][3] += a.w * b.w;
    }
    __syncthreads();
  }
#pragma unroll
  for (int i = 0; i < 4; ++i) {
    float4 r;
    r.x = acc[i][0]; r.y = acc[i][1]; r.z = acc[i][2]; r.w = acc[i][3];
    *(float4*)&C[(size_t)(bm + (ty << 2) + i) * N + bn + (tx << 2)] = r;
  }
}

// ---------------------------------------------------------------------------
// RMSNorm per row: y = w * x * rsqrt(mean(x^2) + eps).  One block per row.
// ---------------------------------------------------------------------------
__global__ __launch_bounds__(256) void rmsnorm_kernel(
    const float* __restrict__ in, const float* __restrict__ w,
    float* __restrict__ out, int len, int istride, int ostride) {
  __shared__ float red[4];
  const int row = blockIdx.x;
  const float* x = in + (size_t)row * istride;
  float* y = out + (size_t)row * ostride;
  float ss = 0.f;
  for (int i = threadIdx.x; i < len; i += 256) { float v = x[i]; ss += v * v; }
#pragma unroll
  for (int o = 32; o > 0; o >>= 1) ss += __shfl_down(ss, o, 64);
  if ((threadIdx.x & 63) == 0) red[threadIdx.x >> 6] = ss;
  __syncthreads();
  if (threadIdx.x == 0)
    red[0] = rsqrtf((red[0] + red[1] + red[2] + red[3]) / (float)len + 1e-6f);
  __syncthreads();
  const float inv = red[0];
  for (int i = threadIdx.x; i < len; i += 256) y[i] = w[i] * (x[i] * inv);
}

// ---------------------------------------------------------------------------
// RoPE: reference does permute_pairs then rotate_half rope; fused this is
//   out[i]    = x[2i]  *cos(p*f_i) - x[2i+1]*sin(p*f_i)      i<32
//   out[32+i] = x[2i+1]*cos(p*f_i) + x[2i]  *sin(p*f_i)
// with f_i = 10000^(-i/32).  ln(10000)/32 = 0.2878231366.
// ---------------------------------------------------------------------------
__device__ __forceinline__ void rope_apply(const float* __restrict__ src,
                                           float* __restrict__ dst, float pos) {
  float xv[64];
#pragma unroll
  for (int i = 0; i < 64; ++i) xv[i] = src[i];
#pragma unroll
  for (int i = 0; i < 32; ++i) {
    float freq = __expf(-0.2878231366f * (float)i);
    float s, c;
    sincosf(pos * freq, &s, &c);
    dst[i]      = xv[2 * i] * c - xv[2 * i + 1] * s;
    dst[i + 32] = xv[2 * i + 1] * c + xv[2 * i] * s;
  }
}

__global__ __launch_bounds__(256) void rope_q_kernel(float* __restrict__ q,
                                                     const int* __restrict__ pos_ids) {
  int idx = blockIdx.x * 256 + threadIdx.x;  // t*16 + h
  if (idx >= B_ * N_ * H_) return;
  int t = idx >> 4, h = idx & 15;
  float* p = q + (size_t)t * (H_ * QHD_) + h * QHD_ + DN_;
  rope_apply(p, p, (float)pos_ids[t]);
}

__global__ __launch_bounds__(256) void rope_k_kernel(const float* __restrict__ kvdn,
                                                     const int* __restrict__ pos_ids,
                                                     float* __restrict__ kpe) {
  int t = blockIdx.x * 256 + threadIdx.x;
  if (t >= B_ * N_) return;
  rope_apply(kvdn + (size_t)t * 576 + 512, kpe + (size_t)t * 64, (float)pos_ids[t]);
}

// ---------------------------------------------------------------------------
// Flash attention, fp32, non-causal (mask is all ones).
// Block: one (b,h), 32-query tile.  Iterate 32-key tiles with online softmax.
// LDS: Q 32x196 (24.5K) + KV 32x196 (24.5K, K then reused for V) + S 32x33.
// Thread (tq=tid>>4, tk=tid&15): scores for q in {2tq,2tq+1}, k in {tk,tk+16};
// PV accumulates out[2 q][8 d] with d = {4tk..4tk+3, 64+4tk..64+4tk+3}.
// ---------------------------------------------------------------------------
__global__ __launch_bounds__(256) void attn_kernel(
    const float* __restrict__ qf,    // (B*N, H*192) roped q_full
    const float* __restrict__ kvup,  // (B*N, H*256) = per head [k_nope(128) | v(128)]
    const float* __restrict__ kpe,   // (B*N, 64) roped shared k_pe
    float* __restrict__ aout) {      // (B*N, H*128)
  __shared__ float Qs[32][196];
  __shared__ float KV[32][196];
  __shared__ float Ss[32][33];
  __shared__ float m_s[32], l_s[32], fac_s[32];

  const int tid = threadIdx.x;
  const int bh = blockIdx.y;
  const int b = bh >> 4;
  const int h = bh & 15;
  const int q0 = blockIdx.x << 5;
  const int tq = tid >> 4;
  const int tk = tid & 15;
  const int base = b * N_;

  for (int idx = tid; idx < 32 * 192; idx += 256) {
    int r = idx / 192, d = idx - r * 192;
    Qs[r][d] = qf[(size_t)(base + q0 + r) * (H_ * QHD_) + h * QHD_ + d];
  }
  if (tid < 32) { m_s[tid] = -1e30f; l_s[tid] = 0.f; }
  float acc[2][8];
#pragma unroll
  for (int i = 0; i < 2; ++i)
#pragma unroll
    for (int j = 0; j < 8; ++j) acc[i][j] = 0.f;
  __syncthreads();

  for (int kt = 0; kt < N_; kt += 32) {
    // --- stage K_full tile (k_nope | k_pe) ---
    for (int idx = tid; idx < 32 * 192; idx += 256) {
      int r = idx / 192, d = idx - r * 192;
      int krow = base + kt + r;
      KV[r][d] = (d < 128) ? kvup[(size_t)krow * 4096 + h * 256 + d]
                           : kpe[(size_t)krow * 64 + (d - 128)];
    }
    __syncthreads();
    // --- scores ---
    float s00 = 0.f, s01 = 0.f, s10 = 0.f, s11 = 0.f;
#pragma unroll
    for (int d4 = 0; d4 < 48; ++d4) {
      float4 qa = *(const float4*)&Qs[2 * tq][d4 << 2];
      float4 qb = *(const float4*)&Qs[2 * tq + 1][d4 << 2];
      float4 ka = *(const float4*)&KV[tk][d4 << 2];
      float4 kb = *(const float4*)&KV[tk + 16][d4 << 2];
      s00 += qa.x * ka.x + qa.y * ka.y + qa.z * ka.z + qa.w * ka.w;
      s01 += qa.x * kb.x + qa.y * kb.y + qa.z * kb.z + qa.w * kb.w;
      s10 += qb.x * ka.x + qb.y * ka.y + qb.z * ka.z + qb.w * ka.w;
      s11 += qb.x * kb.x + qb.y * kb.y + qb.z * kb.z + qb.w * kb.w;
    }
    const float scale = 0.07216878364870323f;  // 1/sqrt(192)
    Ss[2 * tq][tk] = s00 * scale;
    Ss[2 * tq][tk + 16] = s01 * scale;
    Ss[2 * tq + 1][tk] = s10 * scale;
    Ss[2 * tq + 1][tk + 16] = s11 * scale;
    __syncthreads();
    // --- online softmax stats (one thread per query row) ---
    if (tid < 32) {
      const int q = tid;
      float tmax = Ss[q][0];
#pragma unroll
      for (int j = 1; j < 32; ++j) tmax = fmaxf(tmax, Ss[q][j]);
      float mo = m_s[q];
      float mn = fmaxf(mo, tmax);
      float f = __expf(mo - mn);
      float sum = 0.f;
#pragma unroll
      for (int j = 0; j < 32; ++j) {
        float p = __expf(Ss[q][j] - mn);
        Ss[q][j] = p;
        sum += p;
      }
      m_s[q] = mn;
      l_s[q] = l_s[q] * f + sum;
      fac_s[q] = f;
    }
    // --- stage V tile into the (now dead) K buffer ---
    for (int idx = tid; idx < 32 * 128; idx += 256) {
      int r = idx >> 7, d = idx & 127;
      KV[r][d] = kvup[(size_t)(base + kt + r) * 4096 + h * 256 + 128 + d];
    }
    __syncthreads();
    // --- PV accumulate with rescale ---
    const float f0 = fac_s[2 * tq];
    const float f1 = fac_s[2 * tq + 1];
#pragma unroll
    for (int j = 0; j < 8; ++j) { acc[0][j] *= f0; acc[1][j] *= f1; }
#pragma unroll 8
    for (int k = 0; k < 32; ++k) {
      float p0 = Ss[2 * tq][k];
      float p1 = Ss[2 * tq + 1][k];
      float4 va = *(const float4*)&KV[k][tk << 2];
      float4 vb = *(const float4*)&KV[k][64 + (tk << 2)];
      acc[0][0] += p0 * va.x; acc[0][1] += p0 * va.y; acc[0][2] += p0 * va.z; acc[0][3] += p0 * va.w;
      acc[0][4] += p0 * vb.x; acc[0][5] += p0 * vb.y; acc[0][6] += p0 * vb.z; acc[0][7] += p0 * vb.w;
      acc[1][0] += p1 * va.x; acc[1][1] += p1 * va.y; acc[1][2] += p1 * va.z; acc[1][3] += p1 * va.w;
      acc[1][4] += p1 * vb.x; acc[1][5] += p1 * vb.y; acc[1][6] += p1 * vb.z; acc[1][7] += p1 * vb.w;
    }
    __syncthreads();
  }
  // --- normalize and write (B*N, H*128) ---
  const float inv0 = 1.f / l_s[2 * tq];
  const float inv1 = 1.f / l_s[2 * tq + 1];
  size_t row0 = (size_t)(base + q0 + 2 * tq) * (H_ * DV_) + h * DV_;
  size_t row1 = row0 + (H_ * DV_);
  float4 r;
  r.x = acc[0][0] * inv0; r.y = acc[0][1] * inv0; r.z = acc[0][2] * inv0; r.w = acc[0][3] * inv0;
  *(float4*)&aout[row0 + (tk << 2)] = r;
  r.x = acc[0][4] * inv0; r.y = acc[0][5] * inv0; r.z = acc[0][6] * inv0; r.w = acc[0][7] * inv0;
  *(float4*)&aout[row0 + 64 + (tk << 2)] = r;
  r.x = acc[1][0] * inv1; r.y = acc[1][1] * inv1; r.z = acc[1][2] * inv1; r.w = acc[1][3] * inv1;
  *(float4*)&aout[row1 + (tk << 2)] = r;
  r.x = acc[1][4] * inv1; r.y = acc[1][5] * inv1; r.z = acc[1][6] * inv1; r.w = acc[1][7] * inv1;
  *(float4*)&aout[row1 + 64 + (tk << 2)] = r;
}

// ---------------------------------------------------------------------------
extern "C" void kernel_launch(void* const* d_in, const int* in_sizes, int n_in,
                              void* d_out, int out_size, void* d_ws, size_t ws_size,
                              hipStream_t stream) {
  (void)in_sizes; (void)n_in; (void)out_size; (void)ws_size;
  const float* x         = (const float*)d_in[0];
  const float* Wq_down   = (const float*)d_in[1];
  const float* q_norm_w  = (const float*)d_in[2];
  const float* Wq_up     = (const float*)d_in[3];
  const float* Wkv_down  = (const float*)d_in[4];
  const float* kv_norm_w = (const float*)d_in[5];
  const float* Wkv_up    = (const float*)d_in[6];
  const float* Wo        = (const float*)d_in[7];
  // d_in[8] = mask (all ones, ignored)
  const int* pos_ids     = (const int*)d_in[9];
  float* out = (float*)d_out;

  const int M = B_ * N_;  // 4096 token rows
  float* ws    = (float*)d_ws;
  float* q_tmp = ws;                        // M x 1536
  float* q_up  = q_tmp + (size_t)M * QR_;   // M x 3072
  float* kv_dn = q_up + (size_t)M * 3072;   // M x 576
  float* kv_n  = kv_dn + (size_t)M * 576;   // M x 512
  float* kv_up = kv_n + (size_t)M * 512;    // M x 4096
  float* kpe   = kv_up + (size_t)M * 4096;  // M x 64
  float* a_out = kpe + (size_t)M * 64;      // M x 2048

  dim3 blk(256);
  // q path
  gemm_f32_kernel<<<dim3(QR_ / 64, M / 64), blk, 0, stream>>>(x, Wq_down, q_tmp, M, QR_, HID_);
  rmsnorm_kernel<<<dim3(M), blk, 0, stream>>>(q_tmp, q_norm_w, q_tmp, QR_, QR_, QR_);
  gemm_f32_kernel<<<dim3((H_ * QHD_) / 64, M / 64), blk, 0, stream>>>(q_tmp, Wq_up, q_up, M, H_ * QHD_, QR_);
  // kv path
  gemm_f32_kernel<<<dim3(576 / 64, M / 64), blk, 0, stream>>>(x, Wkv_down, kv_dn, M, 576, HID_);
  rmsnorm_kernel<<<dim3(M), blk, 0, stream>>>(kv_dn, kv_norm_w, kv_n, KVR_, 576, KVR_);
  gemm_f32_kernel<<<dim3(4096 / 64, M / 64), blk, 0, stream>>>(kv_n, Wkv_up, kv_up, M, 4096, KVR_);
  // rope
  rope_q_kernel<<<dim3((M * H_) / 256), blk, 0, stream>>>(q_up, pos_ids);
  rope_k_kernel<<<dim3(M / 256), blk, 0, stream>>>(kv_dn, pos_ids, kpe);
  // attention
  attn_kernel<<<dim3(N_ / 32, B_ * H_), blk, 0, stream>>>(q_up, kv_up, kpe, a_out);
  // output projection
  gemm_f32_kernel<<<dim3(HID_ / 64, M / 64), blk, 0, stream>>>(a_out, Wo, out, M, HID_, H_ * DV_);
}

// Round 2
// 2877.719 us; speedup vs baseline: 1.6857x; 1.6857x over previous
//
#include <hip/hip_runtime.h>
#include <hip/hip_bf16.h>
#include <cstdint>

#define B_ 2
#define N_ 2048
#define H_ 16
#define HID_ 2048
#define QR_ 1536
#define KVR_ 512
#define DN_ 128
#define DR_ 64
#define DV_ 128
#define QHD_ 192

typedef __attribute__((ext_vector_type(8))) short short8;
typedef __attribute__((ext_vector_type(4))) float f32x4;

union bfu { __hip_bfloat16 b; short s; };

// split v into bf16 hi (RNE) + bf16 lo of the remainder
static __device__ __forceinline__ void bf_split(float v, short& hi, short& lo) {
  bfu uh, ul;
  uh.b = __float2bfloat16(v);
  float hf = __bfloat162float(uh.b);
  ul.b = __float2bfloat16(v - hf);
  hi = uh.s; lo = ul.s;
}

// ---------------------------------------------------------------------------
// Tiled fp32 GEMM (unchanged from round 0): C[M,N] = A[M,K] @ B[K,N].
// ---------------------------------------------------------------------------
__global__ __launch_bounds__(256) void gemm_f32_kernel(
    const float* __restrict__ A, const float* __restrict__ B,
    float* __restrict__ C, int M, int N, int K) {
  __shared__ float As[16][68];
  __shared__ float Bs[16][68];
  const int tid = threadIdx.x;
  const int bm = blockIdx.y << 6;
  const int bn = blockIdx.x << 6;
  const int ty = tid >> 4;
  const int tx = tid & 15;
  const int la_r = tid >> 2;
  const int la_c = (tid & 3) << 2;
  const int lb_r = tid >> 4;
  const int lb_c = (tid & 15) << 2;
  const float* Aptr = A + (size_t)(bm + la_r) * K + la_c;
  const float* Bptr = B + (size_t)lb_r * N + bn + lb_c;
  float acc[4][4] = {{0.f, 0.f, 0.f, 0.f}};
  for (int kt = 0; kt < K; kt += 16) {
    float4 av = *(const float4*)(Aptr + kt);
    float4 bv = *(const float4*)(Bptr + (size_t)kt * N);
    As[la_c + 0][la_r] = av.x;
    As[la_c + 1][la_r] = av.y;
    As[la_c + 2][la_r] = av.z;
    As[la_c + 3][la_r] = av.w;
    *(float4*)&Bs[lb_r][lb_c] = bv;
    __syncthreads();
#pragma unroll
    for (int k = 0; k < 16; ++k) {
      float4 a = *(const float4*)&As[k][ty << 2];
      float4 b = *(const float4*)&Bs[k][tx << 2];
      acc[0][0] += a.x * b.x; acc[0][1] += a.x * b.y; acc[0][2] += a.x * b.z; acc[0][3] += a.x * b.w;
      acc[1][0] += a.y * b.x; acc[1][1] += a.y * b.y; acc[1][2] += a.y * b.z; acc[1][3] += a.y * b.w;
      acc[2][0] += a.z * b.x; acc[2][1] += a.z * b.y; acc[2][2] += a.z * b.z; acc[2][3] += a.z * b.w;
      acc[3][0] += a.w * b.x; acc[3][1] += a.w * b.y; acc[3][2] += a.w * b.z; acc[3][3] += a.w * b.w;
    }
    __syncthreads();
  }
#pragma unroll
  for (int i = 0; i < 4; ++i) {
    float4 r;
    r.x = acc[i][0]; r.y = acc[i][1]; r.z = acc[i][2]; r.w = acc[i][3];
    *(float4*)&C[(size_t)(bm + (ty << 2) + i) * N + bn + (tx << 2)] = r;
  }
}

// ---------------------------------------------------------------------------
// RMSNorm per row (unchanged)
// ---------------------------------------------------------------------------
__global__ __launch_bounds__(256) void rmsnorm_kernel(
    const float* __restrict__ in, const float* __restrict__ w,
    float* __restrict__ out, int len, int istride, int ostride) {
  __shared__ float red[4];
  const int row = blockIdx.x;
  const float* x = in + (size_t)row * istride;
  float* y = out + (size_t)row * ostride;
  float ss = 0.f;
  for (int i = threadIdx.x; i < len; i += 256) { float v = x[i]; ss += v * v; }
#pragma unroll
  for (int o = 32; o > 0; o >>= 1) ss += __shfl_down(ss, o, 64);
  if ((threadIdx.x & 63) == 0) red[threadIdx.x >> 6] = ss;
  __syncthreads();
  if (threadIdx.x == 0)
    red[0] = rsqrtf((red[0] + red[1] + red[2] + red[3]) / (float)len + 1e-6f);
  __syncthreads();
  const float inv = red[0];
  for (int i = threadIdx.x; i < len; i += 256) y[i] = w[i] * (x[i] * inv);
}

// ---------------------------------------------------------------------------
// RoPE (unchanged math)
// ---------------------------------------------------------------------------
__device__ __forceinline__ void rope_apply(const float* __restrict__ src,
                                           float* __restrict__ dst, float pos) {
  float xv[64];
#pragma unroll
  for (int i = 0; i < 64; ++i) xv[i] = src[i];
#pragma unroll
  for (int i = 0; i < 32; ++i) {
    float freq = __expf(-0.2878231366f * (float)i);
    float s, c;
    sincosf(pos * freq, &s, &c);
    dst[i]      = xv[2 * i] * c - xv[2 * i + 1] * s;
    dst[i + 32] = xv[2 * i + 1] * c + xv[2 * i] * s;
  }
}

__global__ __launch_bounds__(256) void rope_q_kernel(float* __restrict__ q,
                                                     const int* __restrict__ pos_ids) {
  int idx = blockIdx.x * 256 + threadIdx.x;
  if (idx >= B_ * N_ * H_) return;
  int t = idx >> 4, h = idx & 15;
  float* p = q + (size_t)t * (H_ * QHD_) + h * QHD_ + DN_;
  rope_apply(p, p, (float)pos_ids[t]);
}

__global__ __launch_bounds__(256) void rope_k_kernel(const float* __restrict__ kvdn,
                                                     const int* __restrict__ pos_ids,
                                                     float* __restrict__ kpe) {
  int t = blockIdx.x * 256 + threadIdx.x;
  if (t >= B_ * N_) return;
  rope_apply(kvdn + (size_t)t * 576 + 512, kpe + (size_t)t * 64, (float)pos_ids[t]);
}

// ---------------------------------------------------------------------------
// conv_k: build swizzled bf16 hi/lo K_full tile images.
// Per (bh, kt): 32 rows x 768B.  Row r: 48 16B slots; hi slot s=4c+g holds
// d = c*32+g*8 .. +7; lo slot 24+s.  byte = r*768 + (16*slot ^ ((r&7)<<4)).
// ---------------------------------------------------------------------------
__global__ __launch_bounds__(256) void conv_k_kernel(
    const float* __restrict__ kv_up, const float* __restrict__ kpe,
    uint8_t* __restrict__ Kimg) {
  const int kt = blockIdx.x, bh = blockIdx.y;
  const int b = bh >> 4, h = bh & 15;
  uint8_t* tile = Kimg + (size_t)(bh * 64 + kt) * 24576;
  for (int f = threadIdx.x; f < 768; f += 256) {
    int r = f / 24, s = f - r * 24;
    int d = (s >> 2) * 32 + (s & 3) * 8;
    int tok = b * N_ + kt * 32 + r;
    const float* src = (d < 128) ? (kv_up + (size_t)tok * 4096 + h * 256 + d)
                                 : (kpe + (size_t)tok * 64 + (d - 128));
    short8 hi, lo;
#pragma unroll
    for (int j = 0; j < 8; ++j) { short a, bq; bf_split(src[j], a, bq); hi[j] = a; lo[j] = bq; }
    int sw = (r & 7) << 4;
    *(short8*)(tile + r * 768 + ((16 * s) ^ sw)) = hi;
    *(short8*)(tile + r * 768 + ((16 * (24 + s)) ^ sw)) = lo;
  }
}

// ---------------------------------------------------------------------------
// conv_v: build swizzled bf16 hi/lo V-transposed tile images.
// Per (bh, kt): 128 rows(d) x 128B.  Row d: 8 slots; hi slot g holds keys
// 8g..8g+7; lo slot 4+g.  byte = d*128 + (16*slot ^ ((d&7)<<4)).
// ---------------------------------------------------------------------------
__global__ __launch_bounds__(256) void conv_v_kernel(
    const float* __restrict__ kv_up, uint8_t* __restrict__ Vimg) {
  const int kt = blockIdx.x, bh = blockIdx.y;
  const int b = bh >> 4, h = bh & 15;
  uint8_t* tile = Vimg + (size_t)(bh * 64 + kt) * 16384;
  for (int f = threadIdx.x; f < 512; f += 256) {
    int d = f >> 2, gg = f & 3;
    int tok0 = b * N_ + kt * 32 + gg * 8;
    short8 hi, lo;
#pragma unroll
    for (int j = 0; j < 8; ++j) {
      short a, bq;
      bf_split(kv_up[(size_t)(tok0 + j) * 4096 + h * 256 + 128 + d], a, bq);
      hi[j] = a; lo[j] = bq;
    }
    int sw = (d & 7) << 4;
    *(short8*)(tile + d * 128 + ((16 * gg) ^ sw)) = hi;
    *(short8*)(tile + d * 128 + ((16 * (4 + gg)) ^ sw)) = lo;
  }
}

// ---------------------------------------------------------------------------
// MFMA flash attention, bf16 hi/lo split (fp32-equivalent accuracy).
// 256 thr / 4 waves; Q-tile 64 (16 rows per wave); KB=32 keys per step.
// S = Qs*K^T via mfma_f32_16x16x32_bf16 (3 hi/lo terms), fully-parallel
// register softmax over 16-lane row groups, P->LDS swizzled transpose,
// PV via MFMA (3 terms).  LDS 48KB -> 3 blocks/CU.
// ---------------------------------------------------------------------------
__global__ __launch_bounds__(256, 2) void attn_mfma_kernel(
    const float* __restrict__ q_up,   // (B*N, H*192) roped fp32
    const uint8_t* __restrict__ Kimg,
    const uint8_t* __restrict__ Vimg,
    float* __restrict__ aout) {       // (B*N, H*128)
  __shared__ __align__(16) uint8_t Ks[32 * 768];
  __shared__ __align__(16) uint8_t Vs[128 * 128];
  __shared__ __align__(16) uint8_t Ps[4 * 2048];

  const int tid = threadIdx.x;
  const int lane = tid & 63;
  const int wave = tid >> 6;
  const int g = lane >> 4;
  const int lr = lane & 15;
  const int bh = blockIdx.y;
  const int b = bh >> 4, h = bh & 15;
  const int q0 = blockIdx.x << 6;

  // Q fragments in registers, pre-scaled by 1/sqrt(192), hi/lo split
  short8 qhi[6], qlo[6];
  {
    const int tok = b * N_ + q0 + wave * 16 + lr;
    const float* qp = q_up + (size_t)tok * (H_ * QHD_) + h * QHD_;
    const float scale = 0.07216878364870323f;
#pragma unroll
    for (int c = 0; c < 6; ++c) {
      const float* src = qp + c * 32 + g * 8;
#pragma unroll
      for (int j = 0; j < 8; ++j) {
        short a, bq; bf_split(src[j] * scale, a, bq);
        qhi[c][j] = a; qlo[c][j] = bq;
      }
    }
  }

  f32x4 acc_o[8];
#pragma unroll
  for (int i = 0; i < 8; ++i) acc_o[i] = (f32x4){0.f, 0.f, 0.f, 0.f};
  float m_r[4], l_r[4];
#pragma unroll
  for (int j = 0; j < 4; ++j) { m_r[j] = -1e30f; l_r[j] = 0.f; }

  for (int kt = 0; kt < N_ / 32; ++kt) {
    // stage pre-swizzled K/V tile images -> LDS (linear 16B copies)
    {
      const short8* gk = (const short8*)(Kimg + (size_t)(bh * 64 + kt) * 24576);
      const short8* gv = (const short8*)(Vimg + (size_t)(bh * 64 + kt) * 16384);
      short8* lk = (short8*)Ks;
      short8* lv = (short8*)Vs;
#pragma unroll
      for (int i = 0; i < 6; ++i) lk[tid + 256 * i] = gk[tid + 256 * i];
#pragma unroll
      for (int i = 0; i < 4; ++i) lv[tid + 256 * i] = gv[tid + 256 * i];
    }
    __syncthreads();

    // ---- QK^T: 2 key sub-tiles x 6 d-chunks x 3 split terms ----
    f32x4 accs[2];
#pragma unroll
    for (int t = 0; t < 2; ++t) {
      f32x4 a = {0.f, 0.f, 0.f, 0.f};
      const int krow = t * 16 + lr;
      const uint8_t* kb = Ks + krow * 768;
      const int sw = (krow & 7) << 4;
#pragma unroll
      for (int c = 0; c < 6; ++c) {
        short8 kh = *(const short8*)(kb + ((16 * (4 * c + g)) ^ sw));
        short8 kl = *(const short8*)(kb + ((16 * (24 + 4 * c + g)) ^ sw));
        a = __builtin_amdgcn_mfma_f32_16x16x32_bf16(qhi[c], kh, a, 0, 0, 0);
        a = __builtin_amdgcn_mfma_f32_16x16x32_bf16(qhi[c], kl, a, 0, 0, 0);
        a = __builtin_amdgcn_mfma_f32_16x16x32_bf16(qlo[c], kh, a, 0, 0, 0);
      }
      accs[t] = a;
    }

    // ---- online softmax, all-lane parallel (rows g*4+j live in 16-lane group)
    float fac[4], p0[4], p1[4];
#pragma unroll
    for (int j = 0; j < 4; ++j) {
      float rm = fmaxf(accs[0][j], accs[1][j]);
      rm = fmaxf(rm, __shfl_xor(rm, 1, 64));
      rm = fmaxf(rm, __shfl_xor(rm, 2, 64));
      rm = fmaxf(rm, __shfl_xor(rm, 4, 64));
      rm = fmaxf(rm, __shfl_xor(rm, 8, 64));
      float mn = fmaxf(m_r[j], rm);
      fac[j] = __expf(m_r[j] - mn);
      m_r[j] = mn;
      p0[j] = __expf(accs[0][j] - mn);
      p1[j] = __expf(accs[1][j] - mn);
      float rs = p0[j] + p1[j];
      rs += __shfl_xor(rs, 1, 64);
      rs += __shfl_xor(rs, 2, 64);
      rs += __shfl_xor(rs, 4, 64);
      rs += __shfl_xor(rs, 8, 64);
      l_r[j] = l_r[j] * fac[j] + rs;
    }
#pragma unroll
    for (int dt = 0; dt < 8; ++dt) {
#pragma unroll
      for (int j = 0; j < 4; ++j) acc_o[dt][j] *= fac[j];
    }

    // ---- write P (hi/lo) to per-wave swizzled LDS: transpose D->A layout ----
    {
      uint8_t* pw = Ps + wave * 2048;
#pragma unroll
      for (int j = 0; j < 4; ++j) {
        int r = g * 4 + j;
        int rsw = (r & 7) << 4;
        uint8_t* rowp = pw + r * 128;
#pragma unroll
        for (int t = 0; t < 2; ++t) {
          float p = t ? p1[j] : p0[j];
          int k = t * 16 + lr;
          short a, bq; bf_split(p, a, bq);
          *(short*)(rowp + ((((k >> 3) + 0) * 16) ^ rsw) + (k & 7) * 2) = a;
          *(short*)(rowp + ((((k >> 3) + 4) * 16) ^ rsw) + (k & 7) * 2) = bq;
        }
      }
    }

    // ---- PV: A = P(16x32), B = V(32x16) per d-tile, 3 split terms ----
    {
      const uint8_t* pr = Ps + wave * 2048 + lr * 128;
      const int psw = (lr & 7) << 4;
      short8 ph = *(const short8*)(pr + ((16 * g) ^ psw));
      short8 pl = *(const short8*)(pr + ((16 * (4 + g)) ^ psw));
#pragma unroll
      for (int dt = 0; dt < 8; ++dt) {
        int dcol = dt * 16 + lr;
        const uint8_t* vb = Vs + dcol * 128;
        int vsw = (dcol & 7) << 4;
        short8 vh = *(const short8*)(vb + ((16 * g) ^ vsw));
        short8 vl = *(const short8*)(vb + ((16 * (4 + g)) ^ vsw));
        acc_o[dt] = __builtin_amdgcn_mfma_f32_16x16x32_bf16(ph, vh, acc_o[dt], 0, 0, 0);
        acc_o[dt] = __builtin_amdgcn_mfma_f32_16x16x32_bf16(ph, vl, acc_o[dt], 0, 0, 0);
        acc_o[dt] = __builtin_amdgcn_mfma_f32_16x16x32_bf16(pl, vh, acc_o[dt], 0, 0, 0);
      }
    }
    __syncthreads();
  }

  // ---- epilogue: normalize, store fp32 ----
  float inv[4];
#pragma unroll
  for (int j = 0; j < 4; ++j) inv[j] = 1.f / l_r[j];
  const int tokb = b * N_ + q0 + wave * 16 + g * 4;
#pragma unroll
  for (int j = 0; j < 4; ++j) {
    float* orow = aout + (size_t)(tokb + j) * (H_ * DV_) + h * DV_;
#pragma unroll
    for (int dt = 0; dt < 8; ++dt)
      orow[dt * 16 + lr] = acc_o[dt][j] * inv[j];
  }
}

// ---------------------------------------------------------------------------
extern "C" void kernel_launch(void* const* d_in, const int* in_sizes, int n_in,
                              void* d_out, int out_size, void* d_ws, size_t ws_size,
                              hipStream_t stream) {
  (void)in_sizes; (void)n_in; (void)out_size; (void)ws_size;
  const float* x         = (const float*)d_in[0];
  const float* Wq_down   = (const float*)d_in[1];
  const float* q_norm_w  = (const float*)d_in[2];
  const float* Wq_up     = (const float*)d_in[3];
  const float* Wkv_down  = (const float*)d_in[4];
  const float* kv_norm_w = (const float*)d_in[5];
  const float* Wkv_up    = (const float*)d_in[6];
  const float* Wo        = (const float*)d_in[7];
  const int* pos_ids     = (const int*)d_in[9];
  float* out = (float*)d_out;

  const int M = B_ * N_;  // 4096 token rows
  float* ws = (float*)d_ws;
  // ws layout (floats), total M*11840 = 194 MB (<= proven 195 MB):
  //  [0, M*576)           kv_dn        (dead after rope_k)
  //  [M*576, M*1088)      kv_n         (dead after kv_up gemm)
  //  [0, M*1536)          q_tmp        (reuses kv_dn/kv_n after they die)
  //  [M*1536, M*4608)     q_up
  //  [M*4608, M*8704)     kv_up        (dead after convs)
  //  [M*4608, M*6656)     a_out        (aliases dead kv_up)
  //  [M*8704, M*8768)     kpe
  //  [M*8768, M*11840)    Kimg (bytes)
  // Vimg lives in d_out (exact 33.5 MB fit), overwritten by final GEMM.
  float*   kv_dn = ws;
  float*   kv_n  = ws + (size_t)M * 576;
  float*   q_tmp = ws;
  float*   q_up  = ws + (size_t)M * 1536;
  float*   kv_up = ws + (size_t)M * 4608;
  float*   a_out = ws + (size_t)M * 4608;
  float*   kpe   = ws + (size_t)M * 8704;
  uint8_t* Kimg  = (uint8_t*)(ws + (size_t)M * 8768);
  uint8_t* Vimg  = (uint8_t*)d_out;

  dim3 blk(256);
  // kv path first (so q_tmp can reuse kv_dn/kv_n)
  gemm_f32_kernel<<<dim3(576 / 64, M / 64), blk, 0, stream>>>(x, Wkv_down, kv_dn, M, 576, HID_);
  rmsnorm_kernel<<<dim3(M), blk, 0, stream>>>(kv_dn, kv_norm_w, kv_n, KVR_, 576, KVR_);
  gemm_f32_kernel<<<dim3(4096 / 64, M / 64), blk, 0, stream>>>(kv_n, Wkv_up, kv_up, M, 4096, KVR_);
  rope_k_kernel<<<dim3(M / 256), blk, 0, stream>>>(kv_dn, pos_ids, kpe);
  // q path
  gemm_f32_kernel<<<dim3(QR_ / 64, M / 64), blk, 0, stream>>>(x, Wq_down, q_tmp, M, QR_, HID_);
  rmsnorm_kernel<<<dim3(M), blk, 0, stream>>>(q_tmp, q_norm_w, q_tmp, QR_, QR_, QR_);
  gemm_f32_kernel<<<dim3((H_ * QHD_) / 64, M / 64), blk, 0, stream>>>(q_tmp, Wq_up, q_up, M, H_ * QHD_, QR_);
  rope_q_kernel<<<dim3((M * H_) / 256), blk, 0, stream>>>(q_up, pos_ids);
  // bf16 hi/lo tile images
  conv_k_kernel<<<dim3(64, 32), blk, 0, stream>>>(kv_up, kpe, Kimg);
  conv_v_kernel<<<dim3(64, 32), blk, 0, stream>>>(kv_up, Vimg);
  // MFMA flash attention
  attn_mfma_kernel<<<dim3(N_ / 64, B_ * H_), blk, 0, stream>>>(q_up, Kimg, Vimg, a_out);
  // output projection
  gemm_f32_kernel<<<dim3(HID_ / 64, M / 64), blk, 0, stream>>>(a_out, Wo, out, M, HID_, H_ * DV_);
}

// Round 3
// 1221.459 us; speedup vs baseline: 3.9714x; 2.3560x over previous
//
#include <hip/hip_runtime.h>
#include <hip/hip_bf16.h>
#include <cstdint>

#define B_ 2
#define N_ 2048
#define H_ 16
#define HID_ 2048
#define QR_ 1536
#define KVR_ 512
#define DN_ 128
#define DR_ 64
#define DV_ 128
#define QHD_ 192

typedef __attribute__((ext_vector_type(8))) short short8;
typedef __attribute__((ext_vector_type(4))) float f32x4;

union bfu { __hip_bfloat16 b; short s; };

// split v into bf16 hi (RNE) + bf16 lo of the remainder (error ~2^-18 rel)
static __device__ __forceinline__ void bf_split(float v, short& hi, short& lo) {
  bfu uh, ul;
  uh.b = __float2bfloat16(v);
  float hf = __bfloat162float(uh.b);
  ul.b = __float2bfloat16(v - hf);
  hi = uh.s; lo = ul.s;
}

// async global->LDS, 16B per lane; LDS dest = wave-uniform base + lane*16
static __device__ __forceinline__ void gload16(const void* g, void* l) {
  __builtin_amdgcn_global_load_lds(
      (const __attribute__((address_space(1))) uint32_t*)(g),
      (__attribute__((address_space(3))) uint32_t*)(l), 16, 0, 0);
}

// ---------------------------------------------------------------------------
// A-image tile format (shared by A and B operands): per (rb, ks) tile of
// 128 rows x 64 k bf16 = 16KB.  Row r at r*128B; 16B slot s (k = s*8..s*8+7)
// stored at byte ((16*s) ^ ((r&7)<<4)).  Linear 16B-chunk copy == LDS image.
// A3 k-segments: [Ahi | Alo | Ahi];  B3: [Bhi | Bhi | Blo]  (Keff = 3K).
// ---------------------------------------------------------------------------

// conv_a: fp32 A (rows x K, row-major) -> A3 tile image (Keff = 3K)
__global__ __launch_bounds__(256) void conv_a_kernel(
    const float* __restrict__ A, uint8_t* __restrict__ img, int K, int nks, int total) {
  int gid = blockIdx.x * 256 + threadIdx.x;
  if (gid >= total) return;
  int perRow = K >> 3;
  int row = gid / perRow, kc = (gid - row * perRow) << 3;
  const float* src = A + (size_t)row * K + kc;
  short8 hi, lo;
#pragma unroll
  for (int j = 0; j < 8; ++j) { short a, b; bf_split(src[j], a, b); hi[j] = a; lo[j] = b; }
  int mb = row >> 7, r = row & 127, sw = (r & 7) << 4;
  uint8_t* base = img + ((size_t)mb * nks << 14) + r * 128;
  auto put = [&](int p, short8 v) {
    int ks = p >> 6, s = (p >> 3) & 7;
    *(short8*)(base + ((size_t)ks << 14) + ((16 * s) ^ sw)) = v;
  };
  put(kc, hi); put(K + kc, lo); put(2 * K + kc, hi);
}

// conv_b: fp32 B (K x N, row-major) -> B3 tile image at column offset nbase*128
__global__ __launch_bounds__(256) void conv_b_kernel(
    const float* __restrict__ Bw, uint8_t* __restrict__ img, int K, int N,
    int Npad, int nbase, int nks, int total) {
  int gid = blockIdx.x * 256 + threadIdx.x;
  if (gid >= total) return;
  int perN = K >> 3;
  int n = gid / perN, kc = (gid - n * perN) << 3;
  short8 hi = {0,0,0,0,0,0,0,0}, lo = {0,0,0,0,0,0,0,0};
  if (n < N) {
#pragma unroll
    for (int j = 0; j < 8; ++j) {
      short a, b; bf_split(Bw[(size_t)(kc + j) * N + n], a, b); hi[j] = a; lo[j] = b;
    }
  }
  int nn = nbase * 128 + n;
  int nb = nn >> 7, r = nn & 127, sw = (r & 7) << 4;
  uint8_t* base = img + ((size_t)nb * nks << 14) + r * 128;
  auto put = [&](int p, short8 v) {
    int ks = p >> 6, s = (p >> 3) & 7;
    *(short8*)(base + ((size_t)ks << 14) + ((16 * s) ^ sw)) = v;
  };
  put(kc, hi); put(K + kc, hi); put(2 * K + kc, lo);
}

// rmsnorm fused into A3 image emission.  One block per row.
__global__ __launch_bounds__(256) void rmsnorm_img_kernel(
    const float* __restrict__ in, const float* __restrict__ w,
    uint8_t* __restrict__ img, int len, int istride, int nks) {
  __shared__ float red[4];
  const int row = blockIdx.x;
  const float* x = in + (size_t)row * istride;
  float ss = 0.f;
  for (int i = threadIdx.x; i < len; i += 256) { float v = x[i]; ss += v * v; }
#pragma unroll
  for (int o = 32; o > 0; o >>= 1) ss += __shfl_down(ss, o, 64);
  if ((threadIdx.x & 63) == 0) red[threadIdx.x >> 6] = ss;
  __syncthreads();
  if (threadIdx.x == 0)
    red[0] = rsqrtf((red[0] + red[1] + red[2] + red[3]) / (float)len + 1e-6f);
  __syncthreads();
  const float inv = red[0];
  int mb = row >> 7, r = row & 127, sw = (r & 7) << 4;
  uint8_t* base = img + ((size_t)mb * nks << 14) + r * 128;
  auto put = [&](int p, short8 v) {
    int ks = p >> 6, s = (p >> 3) & 7;
    *(short8*)(base + ((size_t)ks << 14) + ((16 * s) ^ sw)) = v;
  };
  for (int kc = threadIdx.x * 8; kc < len; kc += 2048) {
    short8 hi, lo;
#pragma unroll
    for (int j = 0; j < 8; ++j) {
      short a, b; bf_split(w[kc + j] * (x[kc + j] * inv), a, b); hi[j] = a; lo[j] = b;
    }
    put(kc, hi); put(len + kc, lo); put(2 * len + kc, hi);
  }
}

// ---------------------------------------------------------------------------
// bf16 MFMA GEMM: 128x128 tile, BK=64, 4 waves (2x2), 4x4 16x16x32 frags.
// MODE 0: C fp32 row-major (ldc = N).  MODE 1: epilogue writes attention
// K_nope / V tile images (bf16 hi/lo, swizzled) for N=4096 = 16 heads x 256.
// ---------------------------------------------------------------------------
template <int MODE>
__global__ __launch_bounds__(256) void gemm_bf16_kernel(
    const uint8_t* __restrict__ Aimg, const uint8_t* __restrict__ Bimg,
    float* __restrict__ C, int N, int nks,
    uint8_t* __restrict__ Kn, uint8_t* __restrict__ Vv) {
  __shared__ __align__(16) uint8_t As[16384];
  __shared__ __align__(16) uint8_t Bs[16384];
  const int tid = threadIdx.x;
  const int lane = tid & 63;
  const int wave = tid >> 6;
  const int wm = wave >> 1, wn = wave & 1;
  const int lr = lane & 15, g = lane >> 4;
  const int mb = blockIdx.y, nb = blockIdx.x;
  const uint8_t* ga = Aimg + ((size_t)mb * nks << 14);
  const uint8_t* gb = Bimg + ((size_t)nb * nks << 14);

  f32x4 acc[4][4];
#pragma unroll
  for (int i = 0; i < 4; ++i)
#pragma unroll
    for (int j = 0; j < 4; ++j) acc[i][j] = (f32x4){0.f, 0.f, 0.f, 0.f};

  for (int ks = 0; ks < nks; ++ks) {
    __syncthreads();
#pragma unroll
    for (int i = 0; i < 4; ++i)
      gload16(ga + ((size_t)ks << 14) + (wave * 4 + i) * 1024 + lane * 16,
              As + (wave * 4 + i) * 1024);
#pragma unroll
    for (int i = 0; i < 4; ++i)
      gload16(gb + ((size_t)ks << 14) + (wave * 4 + i) * 1024 + lane * 16,
              Bs + (wave * 4 + i) * 1024);
    __syncthreads();
#pragma unroll
    for (int c = 0; c < 2; ++c) {
      short8 af[4], bf[4];
#pragma unroll
      for (int i = 0; i < 4; ++i) {
        int ar = wm * 64 + i * 16 + lr;
        af[i] = *(const short8*)(As + ar * 128 + ((16 * (c * 4 + g)) ^ ((ar & 7) << 4)));
        int br = wn * 64 + i * 16 + lr;
        bf[i] = *(const short8*)(Bs + br * 128 + ((16 * (c * 4 + g)) ^ ((br & 7) << 4)));
      }
#pragma unroll
      for (int i = 0; i < 4; ++i)
#pragma unroll
        for (int j = 0; j < 4; ++j)
          acc[i][j] = __builtin_amdgcn_mfma_f32_16x16x32_bf16(af[i], bf[j], acc[i][j], 0, 0, 0);
    }
  }

  if (MODE == 0) {
#pragma unroll
    for (int i = 0; i < 4; ++i)
#pragma unroll
      for (int q = 0; q < 4; ++q) {
        float* rp = C + (size_t)(mb * 128 + wm * 64 + i * 16 + g * 4 + q) * N +
                    nb * 128 + wn * 64 + lr;
#pragma unroll
        for (int j = 0; j < 4; ++j) rp[j * 16] = acc[i][j][q];
      }
  } else {
    // N = 4096 = 16 heads x [k_nope(128) | v(128)]
#pragma unroll
    for (int i = 0; i < 4; ++i)
#pragma unroll
      for (int j = 0; j < 4; ++j)
#pragma unroll
        for (int q = 0; q < 4; ++q) {
          int trow = mb * 128 + wm * 64 + i * 16 + g * 4 + q;
          int nn = nb * 128 + wn * 64 + j * 16 + lr;
          int h = nn >> 8, half = (nn >> 7) & 1, d = nn & 127;
          int b = trow >> 11, t = trow & 2047, kt = t >> 5, r = t & 31;
          int bh = b * 16 + h;
          short hi, lo; bf_split(acc[i][j][q], hi, lo);
          if (half == 0) {
            uint8_t* tp = Kn + (((size_t)bh * 64 + kt) << 14) + r * 512;
            int sw = (r & 7) << 4, s = d >> 3;
            *(short*)(tp + ((16 * s) ^ sw) + (d & 7) * 2) = hi;
            *(short*)(tp + ((16 * (s + 16)) ^ sw) + (d & 7) * 2) = lo;
          } else {
            uint8_t* tp = Vv + (((size_t)bh * 64 + kt) << 14) + d * 128;
            int sw = (d & 7) << 4, gg = r >> 3;
            *(short*)(tp + ((16 * gg) ^ sw) + (r & 7) * 2) = hi;
            *(short*)(tp + ((16 * (gg + 4)) ^ sw) + (r & 7) * 2) = lo;
          }
        }
  }
}

// ---------------------------------------------------------------------------
// RoPE (permute_pairs + rotate_half fused):
//   out[i] = x[2i]*cos - x[2i+1]*sin ; out[32+i] = x[2i+1]*cos + x[2i]*sin
// ---------------------------------------------------------------------------
__device__ __forceinline__ void rope_apply(const float* __restrict__ src,
                                           float* __restrict__ dst, float pos) {
  float xv[64];
#pragma unroll
  for (int i = 0; i < 64; ++i) xv[i] = src[i];
#pragma unroll
  for (int i = 0; i < 32; ++i) {
    float freq = __expf(-0.2878231366f * (float)i);
    float s, c;
    sincosf(pos * freq, &s, &c);
    dst[i]      = xv[2 * i] * c - xv[2 * i + 1] * s;
    dst[i + 32] = xv[2 * i + 1] * c + xv[2 * i] * s;
  }
}

__global__ __launch_bounds__(256) void rope_q_kernel(float* __restrict__ q,
                                                     const int* __restrict__ pos_ids) {
  int idx = blockIdx.x * 256 + threadIdx.x;  // t*16 + h
  if (idx >= B_ * N_ * H_) return;
  int t = idx >> 4, h = idx & 15;
  float* p = q + (size_t)t * (H_ * QHD_) + h * QHD_ + DN_;
  rope_apply(p, p, (float)pos_ids[t]);
}

// rope_k -> kpe tile image: per (b,kt) 32 rows x 256B (hi slots 0-7, lo 8-15)
__global__ __launch_bounds__(256) void rope_k_kernel(const float* __restrict__ Cmat,
                                                     const int* __restrict__ pos_ids,
                                                     uint8_t* __restrict__ Kp) {
  int t = blockIdx.x * 256 + threadIdx.x;
  if (t >= B_ * N_) return;
  float rv[64];
  rope_apply(Cmat + (size_t)t * 2176 + 2048, rv, (float)pos_ids[t]);
  int b = t >> 11, tt = t & 2047, kt = tt >> 5, r = tt & 31;
  uint8_t* tp = Kp + (((size_t)b * 64 + kt) << 13) + r * 256;
  int sw = (r & 7) << 4;
#pragma unroll
  for (int s = 0; s < 8; ++s) {
    short8 hi, lo;
#pragma unroll
    for (int j = 0; j < 8; ++j) { short a, bq; bf_split(rv[s * 8 + j], a, bq); hi[j] = a; lo[j] = bq; }
    *(short8*)(tp + ((16 * s) ^ sw)) = hi;
    *(short8*)(tp + ((16 * (s + 8)) ^ sw)) = lo;
  }
}

// ---------------------------------------------------------------------------
// MFMA flash attention (bf16 hi/lo).  4 waves x 16 q-rows; KB=32.
// K sources: Kn img (k_nope, 32x512B tiles) + Kp img (k_pe, 32x256B tiles),
// V img (128x128B tiles), all pre-swizzled; staged with global_load_lds.
// ---------------------------------------------------------------------------
__global__ __launch_bounds__(256, 3) void attn_mfma_kernel(
    const float* __restrict__ q_up,   // (B*N, H*192) roped fp32
    const uint8_t* __restrict__ Kn, const uint8_t* __restrict__ Kp,
    const uint8_t* __restrict__ Vv,
    float* __restrict__ aout) {       // (B*N, H*128)
  __shared__ __align__(16) uint8_t Ksn[32 * 512];
  __shared__ __align__(16) uint8_t Ksp[32 * 256];
  __shared__ __align__(16) uint8_t Vs[128 * 128];
  __shared__ __align__(16) uint8_t Ps[4 * 2048];

  const int tid = threadIdx.x;
  const int lane = tid & 63;
  const int wave = tid >> 6;
  const int g = lane >> 4;
  const int lr = lane & 15;
  const int bh = blockIdx.y;
  const int b = bh >> 4, h = bh & 15;
  const int q0 = blockIdx.x << 6;

  short8 qhi[6], qlo[6];
  {
    const int tok = b * N_ + q0 + wave * 16 + lr;
    const float* qp = q_up + (size_t)tok * (H_ * QHD_) + h * QHD_;
    const float scale = 0.07216878364870323f;  // 1/sqrt(192)
#pragma unroll
    for (int c = 0; c < 6; ++c) {
      const float* src = qp + c * 32 + g * 8;
#pragma unroll
      for (int j = 0; j < 8; ++j) {
        short a, bq; bf_split(src[j] * scale, a, bq);
        qhi[c][j] = a; qlo[c][j] = bq;
      }
    }
  }

  f32x4 acc_o[8];
#pragma unroll
  for (int i = 0; i < 8; ++i) acc_o[i] = (f32x4){0.f, 0.f, 0.f, 0.f};
  float m_r[4], l_r[4];
#pragma unroll
  for (int j = 0; j < 4; ++j) { m_r[j] = -1e30f; l_r[j] = 0.f; }

  for (int kt = 0; kt < N_ / 32; ++kt) {
    __syncthreads();
    {
      const uint8_t* gkn = Kn + (((size_t)bh * 64 + kt) << 14);
      const uint8_t* gkp = Kp + (((size_t)b * 64 + kt) << 13);
      const uint8_t* gv  = Vv + (((size_t)bh * 64 + kt) << 14);
#pragma unroll
      for (int i = 0; i < 4; ++i)
        gload16(gkn + (wave * 4 + i) * 1024 + lane * 16, Ksn + (wave * 4 + i) * 1024);
#pragma unroll
      for (int i = 0; i < 2; ++i)
        gload16(gkp + (wave * 2 + i) * 1024 + lane * 16, Ksp + (wave * 2 + i) * 1024);
#pragma unroll
      for (int i = 0; i < 4; ++i)
        gload16(gv + (wave * 4 + i) * 1024 + lane * 16, Vs + (wave * 4 + i) * 1024);
    }
    __syncthreads();

    // ---- QK^T ----
    f32x4 accs[2];
#pragma unroll
    for (int t = 0; t < 2; ++t) {
      f32x4 a = {0.f, 0.f, 0.f, 0.f};
      const int krow = t * 16 + lr;
      const int sw = (krow & 7) << 4;
      const uint8_t* kb = Ksn + krow * 512;
#pragma unroll
      for (int c = 0; c < 4; ++c) {
        short8 kh = *(const short8*)(kb + ((16 * (c * 4 + g)) ^ sw));
        short8 kl = *(const short8*)(kb + ((16 * (c * 4 + g + 16)) ^ sw));
        a = __builtin_amdgcn_mfma_f32_16x16x32_bf16(qhi[c], kh, a, 0, 0, 0);
        a = __builtin_amdgcn_mfma_f32_16x16x32_bf16(qhi[c], kl, a, 0, 0, 0);
        a = __builtin_amdgcn_mfma_f32_16x16x32_bf16(qlo[c], kh, a, 0, 0, 0);
      }
      const uint8_t* pb = Ksp + krow * 256;
#pragma unroll
      for (int c2 = 0; c2 < 2; ++c2) {
        short8 kh = *(const short8*)(pb + ((16 * (c2 * 4 + g)) ^ sw));
        short8 kl = *(const short8*)(pb + ((16 * (c2 * 4 + g + 8)) ^ sw));
        a = __builtin_amdgcn_mfma_f32_16x16x32_bf16(qhi[4 + c2], kh, a, 0, 0, 0);
        a = __builtin_amdgcn_mfma_f32_16x16x32_bf16(qhi[4 + c2], kl, a, 0, 0, 0);
        a = __builtin_amdgcn_mfma_f32_16x16x32_bf16(qlo[4 + c2], kh, a, 0, 0, 0);
      }
      accs[t] = a;
    }

    // ---- online softmax (row = g*4+j lives in 16-lane group) ----
    float fac[4], p0[4], p1[4];
#pragma unroll
    for (int j = 0; j < 4; ++j) {
      float rm = fmaxf(accs[0][j], accs[1][j]);
      rm = fmaxf(rm, __shfl_xor(rm, 1, 64));
      rm = fmaxf(rm, __shfl_xor(rm, 2, 64));
      rm = fmaxf(rm, __shfl_xor(rm, 4, 64));
      rm = fmaxf(rm, __shfl_xor(rm, 8, 64));
      float mn = fmaxf(m_r[j], rm);
      fac[j] = __expf(m_r[j] - mn);
      m_r[j] = mn;
      p0[j] = __expf(accs[0][j] - mn);
      p1[j] = __expf(accs[1][j] - mn);
      float rs = p0[j] + p1[j];
      rs += __shfl_xor(rs, 1, 64);
      rs += __shfl_xor(rs, 2, 64);
      rs += __shfl_xor(rs, 4, 64);
      rs += __shfl_xor(rs, 8, 64);
      l_r[j] = l_r[j] * fac[j] + rs;
    }
#pragma unroll
    for (int dt = 0; dt < 8; ++dt) {
#pragma unroll
      for (int j = 0; j < 4; ++j) acc_o[dt][j] *= fac[j];
    }

    // ---- P (hi/lo) -> per-wave swizzled LDS (transpose D->A layout) ----
    {
      uint8_t* pw = Ps + wave * 2048;
#pragma unroll
      for (int j = 0; j < 4; ++j) {
        int r = g * 4 + j;
        int rsw = (r & 7) << 4;
        uint8_t* rowp = pw + r * 128;
#pragma unroll
        for (int t = 0; t < 2; ++t) {
          float p = t ? p1[j] : p0[j];
          int k = t * 16 + lr;
          short a, bq; bf_split(p, a, bq);
          *(short*)(rowp + ((((k >> 3) + 0) * 16) ^ rsw) + (k & 7) * 2) = a;
          *(short*)(rowp + ((((k >> 3) + 4) * 16) ^ rsw) + (k & 7) * 2) = bq;
        }
      }
    }

    // ---- PV ----
    {
      const uint8_t* pr = Ps + wave * 2048 + lr * 128;
      const int psw = (lr & 7) << 4;
      short8 ph = *(const short8*)(pr + ((16 * g) ^ psw));
      short8 pl = *(const short8*)(pr + ((16 * (4 + g)) ^ psw));
#pragma unroll
      for (int dt = 0; dt < 8; ++dt) {
        int dcol = dt * 16 + lr;
        const uint8_t* vb = Vs + dcol * 128;
        int vsw = (dcol & 7) << 4;
        short8 vh = *(const short8*)(vb + ((16 * g) ^ vsw));
        short8 vl = *(const short8*)(vb + ((16 * (4 + g)) ^ vsw));
        acc_o[dt] = __builtin_amdgcn_mfma_f32_16x16x32_bf16(ph, vh, acc_o[dt], 0, 0, 0);
        acc_o[dt] = __builtin_amdgcn_mfma_f32_16x16x32_bf16(ph, vl, acc_o[dt], 0, 0, 0);
        acc_o[dt] = __builtin_amdgcn_mfma_f32_16x16x32_bf16(pl, vh, acc_o[dt], 0, 0, 0);
      }
    }
  }

  float inv[4];
#pragma unroll
  for (int j = 0; j < 4; ++j) inv[j] = 1.f / l_r[j];
  const int tokb = b * N_ + q0 + wave * 16 + g * 4;
#pragma unroll
  for (int j = 0; j < 4; ++j) {
    float* orow = aout + (size_t)(tokb + j) * (H_ * DV_) + h * DV_;
#pragma unroll
    for (int dt = 0; dt < 8; ++dt)
      orow[dt * 16 + lr] = acc_o[dt][j] * inv[j];
  }
}

// ---------------------------------------------------------------------------
extern "C" void kernel_launch(void* const* d_in, const int* in_sizes, int n_in,
                              void* d_out, int out_size, void* d_ws, size_t ws_size,
                              hipStream_t stream) {
  (void)in_sizes; (void)n_in; (void)out_size; (void)ws_size;
  const float* x         = (const float*)d_in[0];
  const float* Wq_down   = (const float*)d_in[1];
  const float* q_norm_w  = (const float*)d_in[2];
  const float* Wq_up     = (const float*)d_in[3];
  const float* Wkv_down  = (const float*)d_in[4];
  const float* kv_norm_w = (const float*)d_in[5];
  const float* Wkv_up    = (const float*)d_in[6];
  const float* Wo        = (const float*)d_in[7];
  const int* pos_ids     = (const int*)d_in[9];
  float* out = (float*)d_out;

  // ws byte layout (peak 165.7MB < 194MB proven):
  //  [0, 50.33M)        A_slot: x-img -> q-img -> kv-img;  later a_out fp32 [0,33.55M)
  //  [50.33M, 78.64M)   B_slot (rotating weight images);   later a-img [50.33M,100.66M)
  //  [78.64M, 128.97M)  q_up fp32 (M x 3072);              later Wo-img [100.66M,125.83M)
  //  [128.97M, 164.63M) q_tmp/kv_dn combined C (M x 2176); later Kn img [128.97M,162.53M)
  //  [164.63M, 165.68M) kpe img
  //  Vimg = d_out (exact 33.55MB fit; dead before final GEMM writes out)
  uint8_t* W = (uint8_t*)d_ws;
  uint8_t* Aimg  = W;
  uint8_t* Bimg  = W + 50331648;
  float*   q_up  = (float*)(W + 78643200);
  float*   qtkv  = (float*)(W + 128974848);
  uint8_t* Knimg = W + 128974848;
  uint8_t* Kpimg = W + 164626432;
  float*   a_out = (float*)(W + 0);
  uint8_t* Aimg2 = W + 50331648;
  uint8_t* Woimg = W + 100663296;
  uint8_t* Vimg  = (uint8_t*)d_out;

  dim3 blk(256);
  // x -> A3 image; combined [Wq_down | Wkv_down] -> B3 image; one down-proj GEMM
  conv_a_kernel<<<4096, blk, 0, stream>>>(x, Aimg, 2048, 96, 4096 * 256);
  conv_b_kernel<<<1536, blk, 0, stream>>>(Wq_down, Bimg, 2048, 1536, 1536, 0, 96, 1536 * 256);
  conv_b_kernel<<<640, blk, 0, stream>>>(Wkv_down, Bimg, 2048, 576, 640, 12, 96, 640 * 256);
  gemm_bf16_kernel<0><<<dim3(17, 32), blk, 0, stream>>>(Aimg, Bimg, qtkv, 2176, 96, nullptr, nullptr);
  // q path: rmsnorm->img, Wq_up GEMM, rope
  rmsnorm_img_kernel<<<4096, blk, 0, stream>>>(qtkv, q_norm_w, Aimg, 1536, 2176, 72);
  conv_b_kernel<<<2304, blk, 0, stream>>>(Wq_up, Bimg, 1536, 3072, 3072, 0, 72, 2304 * 256);
  gemm_bf16_kernel<0><<<dim3(24, 32), blk, 0, stream>>>(Aimg, Bimg, q_up, 3072, 72, nullptr, nullptr);
  rope_q_kernel<<<256, blk, 0, stream>>>(q_up, pos_ids);
  // kv path: rope_k -> kpe img; rmsnorm->img; Wkv_up GEMM -> Kn/V images
  rope_k_kernel<<<16, blk, 0, stream>>>(qtkv, pos_ids, Kpimg);
  rmsnorm_img_kernel<<<4096, blk, 0, stream>>>(qtkv + 1536, kv_norm_w, Aimg, 512, 2176, 24);
  conv_b_kernel<<<1024, blk, 0, stream>>>(Wkv_up, Bimg, 512, 4096, 4096, 0, 24, 1024 * 256);
  gemm_bf16_kernel<1><<<dim3(32, 32), blk, 0, stream>>>(Aimg, Bimg, nullptr, 4096, 24, Knimg, Vimg);
  // attention
  attn_mfma_kernel<<<dim3(32, 32), blk, 0, stream>>>(q_up, Knimg, Kpimg, Vimg, a_out);
  // output projection
  conv_a_kernel<<<4096, blk, 0, stream>>>(a_out, Aimg2, 2048, 96, 4096 * 256);
  conv_b_kernel<<<2048, blk, 0, stream>>>(Wo, Woimg, 2048, 2048, 2048, 0, 96, 2048 * 256);
  gemm_bf16_kernel<0><<<dim3(16, 32), blk, 0, stream>>>(Aimg2, Woimg, out, 2048, 96, nullptr, nullptr);
}

// Round 6
// 1169.458 us; speedup vs baseline: 4.1479x; 1.0445x over previous
//
#include <hip/hip_runtime.h>
#include <hip/hip_bf16.h>
#include <cstdint>

#define B_ 2
#define N_ 2048
#define H_ 16
#define HID_ 2048
#define QR_ 1536
#define KVR_ 512
#define DN_ 128
#define DR_ 64
#define DV_ 128
#define QHD_ 192

typedef __attribute__((ext_vector_type(8))) short short8;
typedef __attribute__((ext_vector_type(4))) float f32x4;

union bfu { __hip_bfloat16 b; short s; };

// split v into bf16 hi (RNE) + bf16 lo of the remainder (error ~2^-18 rel)
static __device__ __forceinline__ void bf_split(float v, short& hi, short& lo) {
  bfu uh, ul;
  uh.b = __float2bfloat16(v);
  float hf = __bfloat162float(uh.b);
  ul.b = __float2bfloat16(v - hf);
  hi = uh.s; lo = ul.s;
}

// async global->LDS, 16B per lane; LDS dest = wave-uniform base + lane*16
static __device__ __forceinline__ void gload16(const void* g, void* l) {
  __builtin_amdgcn_global_load_lds(
      (const __attribute__((address_space(1))) uint32_t*)(g),
      (__attribute__((address_space(3))) uint32_t*)(l), 16, 0, 0);
}

// ---------------------------------------------------------------------------
// Tile-image format: per (rowblock, ks) tile of 128 rows x 64 k bf16 = 16KB.
// Row r at r*128B; 16B slot s (k = s*8..s*8+7) at byte ((16*s) ^ ((r&7)<<4)).
// A3 k-segments: [Ahi | Alo | Ahi];  B3: [Bhi | Bhi | Blo]  (Keff = 3K).
// ---------------------------------------------------------------------------

__global__ __launch_bounds__(256) void conv_a_kernel(
    const float* __restrict__ A, uint8_t* __restrict__ img, int K, int nks, int total) {
  int gid = blockIdx.x * 256 + threadIdx.x;
  if (gid >= total) return;
  int perRow = K >> 3;
  int row = gid / perRow, kc = (gid - row * perRow) << 3;
  const float* src = A + (size_t)row * K + kc;
  short8 hi, lo;
#pragma unroll
  for (int j = 0; j < 8; ++j) { short a, b; bf_split(src[j], a, b); hi[j] = a; lo[j] = b; }
  int mb = row >> 7, r = row & 127, sw = (r & 7) << 4;
  uint8_t* base = img + ((size_t)mb * nks << 14) + r * 128;
  auto put = [&](int p, short8 v) {
    int ks = p >> 6, s = (p >> 3) & 7;
    *(short8*)(base + ((size_t)ks << 14) + ((16 * s) ^ sw)) = v;
  };
  put(kc, hi); put(K + kc, lo); put(2 * K + kc, hi);
}

__global__ __launch_bounds__(256) void conv_b_kernel(
    const float* __restrict__ Bw, uint8_t* __restrict__ img, int K, int N,
    int Npad, int nbase, int nks, int total) {
  int gid = blockIdx.x * 256 + threadIdx.x;
  if (gid >= total) return;
  int perN = K >> 3;
  int n = gid / perN, kc = (gid - n * perN) << 3;
  short8 hi = {0,0,0,0,0,0,0,0}, lo = {0,0,0,0,0,0,0,0};
  if (n < N) {
#pragma unroll
    for (int j = 0; j < 8; ++j) {
      short a, b; bf_split(Bw[(size_t)(kc + j) * N + n], a, b); hi[j] = a; lo[j] = b;
    }
  }
  int nn = nbase * 128 + n;
  int nb = nn >> 7, r = nn & 127, sw = (r & 7) << 4;
  uint8_t* base = img + ((size_t)nb * nks << 14) + r * 128;
  auto put = [&](int p, short8 v) {
    int ks = p >> 6, s = (p >> 3) & 7;
    *(short8*)(base + ((size_t)ks << 14) + ((16 * s) ^ sw)) = v;
  };
  put(kc, hi); put(K + kc, hi); put(2 * K + kc, lo);
}

// rmsnorm fused into A3 image emission.  One block per row.
__global__ __launch_bounds__(256) void rmsnorm_img_kernel(
    const float* __restrict__ in, const float* __restrict__ w,
    uint8_t* __restrict__ img, int len, int istride, int nks) {
  __shared__ float red[4];
  const int row = blockIdx.x;
  const float* x = in + (size_t)row * istride;
  float ss = 0.f;
  for (int i = threadIdx.x; i < len; i += 256) { float v = x[i]; ss += v * v; }
#pragma unroll
  for (int o = 32; o > 0; o >>= 1) ss += __shfl_down(ss, o, 64);
  if ((threadIdx.x & 63) == 0) red[threadIdx.x >> 6] = ss;
  __syncthreads();
  if (threadIdx.x == 0)
    red[0] = rsqrtf((red[0] + red[1] + red[2] + red[3]) / (float)len + 1e-6f);
  __syncthreads();
  const float inv = red[0];
  int mb = row >> 7, r = row & 127, sw = (r & 7) << 4;
  uint8_t* base = img + ((size_t)mb * nks << 14) + r * 128;
  auto put = [&](int p, short8 v) {
    int ks = p >> 6, s = (p >> 3) & 7;
    *(short8*)(base + ((size_t)ks << 14) + ((16 * s) ^ sw)) = v;
  };
  for (int kc = threadIdx.x * 8; kc < len; kc += 2048) {
    short8 hi, lo;
#pragma unroll
    for (int j = 0; j < 8; ++j) {
      short a, b; bf_split(w[kc + j] * (x[kc + j] * inv), a, b); hi[j] = a; lo[j] = b;
    }
    put(kc, hi); put(len + kc, lo); put(2 * len + kc, hi);
  }
}

// ---------------------------------------------------------------------------
// bf16 MFMA GEMM: 128x128 tile, BK=64, 4 waves (2x2), 4x4 16x16x32 frags.
// C fp32 row-major (ldc = N).
// ---------------------------------------------------------------------------
__global__ __launch_bounds__(256) void gemm_bf16_kernel(
    const uint8_t* __restrict__ Aimg, const uint8_t* __restrict__ Bimg,
    float* __restrict__ C, int N, int nks) {
  __shared__ __align__(16) uint8_t As[16384];
  __shared__ __align__(16) uint8_t Bs[16384];
  const int tid = threadIdx.x;
  const int lane = tid & 63;
  const int wave = tid >> 6;
  const int wm = wave >> 1, wn = wave & 1;
  const int lr = lane & 15, g = lane >> 4;
  const int mb = blockIdx.y, nb = blockIdx.x;
  const uint8_t* ga = Aimg + ((size_t)mb * nks << 14);
  const uint8_t* gb = Bimg + ((size_t)nb * nks << 14);

  f32x4 acc[4][4];
#pragma unroll
  for (int i = 0; i < 4; ++i)
#pragma unroll
    for (int j = 0; j < 4; ++j) acc[i][j] = (f32x4){0.f, 0.f, 0.f, 0.f};

  for (int ks = 0; ks < nks; ++ks) {
    __syncthreads();
#pragma unroll
    for (int i = 0; i < 4; ++i)
      gload16(ga + ((size_t)ks << 14) + (wave * 4 + i) * 1024 + lane * 16,
              As + (wave * 4 + i) * 1024);
#pragma unroll
    for (int i = 0; i < 4; ++i)
      gload16(gb + ((size_t)ks << 14) + (wave * 4 + i) * 1024 + lane * 16,
              Bs + (wave * 4 + i) * 1024);
    __syncthreads();
#pragma unroll
    for (int c = 0; c < 2; ++c) {
      short8 af[4], bf[4];
#pragma unroll
      for (int i = 0; i < 4; ++i) {
        int ar = wm * 64 + i * 16 + lr;
        af[i] = *(const short8*)(As + ar * 128 + ((16 * (c * 4 + g)) ^ ((ar & 7) << 4)));
        int br = wn * 64 + i * 16 + lr;
        bf[i] = *(const short8*)(Bs + br * 128 + ((16 * (c * 4 + g)) ^ ((br & 7) << 4)));
      }
#pragma unroll
      for (int i = 0; i < 4; ++i)
#pragma unroll
        for (int j = 0; j < 4; ++j)
          acc[i][j] = __builtin_amdgcn_mfma_f32_16x16x32_bf16(af[i], bf[j], acc[i][j], 0, 0, 0);
    }
  }
#pragma unroll
  for (int i = 0; i < 4; ++i)
#pragma unroll
    for (int q = 0; q < 4; ++q) {
      float* rp = C + (size_t)(mb * 128 + wm * 64 + i * 16 + g * 4 + q) * N +
                  nb * 128 + wn * 64 + lr;
#pragma unroll
      for (int j = 0; j < 4; ++j) rp[j * 16] = acc[i][j][q];
    }
}

// ---------------------------------------------------------------------------
// conv_kn: kv_up fp32 -> K_nope tile image (32 rows x 512B per (bh,kt) tile).
// hi slot s = d>>3 (s<16), lo slot s+16;  byte = r*512 + ((16*s)^((r&7)<<4)).
// ---------------------------------------------------------------------------
__global__ __launch_bounds__(256) void conv_kn_kernel(
    const float* __restrict__ kv_up, uint8_t* __restrict__ Kn) {
  const int kt = blockIdx.x, bh = blockIdx.y;
  const int b = bh >> 4, h = bh & 15;
  uint8_t* tile = Kn + (((size_t)bh * 64 + kt) << 14);
  for (int f = threadIdx.x; f < 512; f += 256) {
    int r = f >> 4, s = f & 15;
    int tok = b * N_ + kt * 32 + r;
    const float* src = kv_up + (size_t)tok * 4096 + h * 256 + s * 8;
    short8 hi, lo;
#pragma unroll
    for (int j = 0; j < 8; ++j) { short a, bq; bf_split(src[j], a, bq); hi[j] = a; lo[j] = bq; }
    int sw = (r & 7) << 4;
    *(short8*)(tile + r * 512 + ((16 * s) ^ sw)) = hi;
    *(short8*)(tile + r * 512 + ((16 * (s + 16)) ^ sw)) = lo;
  }
}

// ---------------------------------------------------------------------------
// conv_v: kv_up fp32 -> V-transposed tile image (128 d-rows x 128B per tile).
// Row d: hi slot g (keys 8g..8g+7), lo slot 4+g; byte = d*128 + ((16*slot)^((d&7)<<4))
// ---------------------------------------------------------------------------
__global__ __launch_bounds__(256) void conv_v_kernel(
    const float* __restrict__ kv_up, uint8_t* __restrict__ Vimg) {
  const int kt = blockIdx.x, bh = blockIdx.y;
  const int b = bh >> 4, h = bh & 15;
  uint8_t* tile = Vimg + (((size_t)bh * 64 + kt) << 14);
  for (int f = threadIdx.x; f < 512; f += 256) {
    int d = f >> 2, gg = f & 3;
    int tok0 = b * N_ + kt * 32 + gg * 8;
    short8 hi, lo;
#pragma unroll
    for (int j = 0; j < 8; ++j) {
      short a, bq;
      bf_split(kv_up[(size_t)(tok0 + j) * 4096 + h * 256 + 128 + d], a, bq);
      hi[j] = a; lo[j] = bq;
    }
    int sw = (d & 7) << 4;
    *(short8*)(tile + d * 128 + ((16 * gg) ^ sw)) = hi;
    *(short8*)(tile + d * 128 + ((16 * (4 + gg)) ^ sw)) = lo;
  }
}

// ---------------------------------------------------------------------------
// RoPE (permute_pairs + rotate_half fused)
// ---------------------------------------------------------------------------
__device__ __forceinline__ void rope_apply(const float* __restrict__ src,
                                           float* __restrict__ dst, float pos) {
  float xv[64];
#pragma unroll
  for (int i = 0; i < 64; ++i) xv[i] = src[i];
#pragma unroll
  for (int i = 0; i < 32; ++i) {
    float freq = __expf(-0.2878231366f * (float)i);
    float s, c;
    sincosf(pos * freq, &s, &c);
    dst[i]      = xv[2 * i] * c - xv[2 * i + 1] * s;
    dst[i + 32] = xv[2 * i + 1] * c + xv[2 * i] * s;
  }
}

__global__ __launch_bounds__(256) void rope_q_kernel(float* __restrict__ q,
                                                     const int* __restrict__ pos_ids) {
  int idx = blockIdx.x * 256 + threadIdx.x;  // t*16 + h
  if (idx >= B_ * N_ * H_) return;
  int t = idx >> 4, h = idx & 15;
  float* p = q + (size_t)t * (H_ * QHD_) + h * QHD_ + DN_;
  rope_apply(p, p, (float)pos_ids[t]);
}

// rope_k -> kpe tile image: per (b,kt) 32 rows x 256B (hi slots 0-7, lo 8-15)
__global__ __launch_bounds__(256) void rope_k_kernel(const float* __restrict__ Cmat,
                                                     const int* __restrict__ pos_ids,
                                                     uint8_t* __restrict__ Kp) {
  int t = blockIdx.x * 256 + threadIdx.x;
  if (t >= B_ * N_) return;
  float rv[64];
  rope_apply(Cmat + (size_t)t * 2176 + 2048, rv, (float)pos_ids[t]);
  int b = t >> 11, tt = t & 2047, kt = tt >> 5, r = tt & 31;
  uint8_t* tp = Kp + (((size_t)b * 64 + kt) << 13) + r * 256;
  int sw = (r & 7) << 4;
#pragma unroll
  for (int s = 0; s < 8; ++s) {
    short8 hi, lo;
#pragma unroll
    for (int j = 0; j < 8; ++j) { short a, bq; bf_split(rv[s * 8 + j], a, bq); hi[j] = a; lo[j] = bq; }
    *(short8*)(tp + ((16 * s) ^ sw)) = hi;
    *(short8*)(tp + ((16 * (s + 8)) ^ sw)) = lo;
  }
}

// ---------------------------------------------------------------------------
// MFMA flash attention (bf16 hi/lo).  4 waves x 32 q-rows (2 fragment tiles)
// = 128 q-rows/block; KB=32.  Each K/V LDS fragment read feeds 6 MFMAs
// (2 q-tiles x 3 hi/lo terms) -> ~2x less LDS read traffic per q*key.
// ---------------------------------------------------------------------------
__global__ __launch_bounds__(256, 2) void attn_mfma_kernel(
    const float* __restrict__ q_up,   // (B*N, H*192) roped fp32
    const uint8_t* __restrict__ Kn, const uint8_t* __restrict__ Kp,
    const uint8_t* __restrict__ Vv,
    float* __restrict__ aout) {       // (B*N, H*128)
  __shared__ __align__(16) uint8_t Ksn[32 * 512];
  __shared__ __align__(16) uint8_t Ksp[32 * 256];
  __shared__ __align__(16) uint8_t Vs[128 * 128];
  __shared__ __align__(16) uint8_t Ps[4 * 4096];

  const int tid = threadIdx.x;
  const int lane = tid & 63;
  const int wave = tid >> 6;
  const int g = lane >> 4;
  const int lr = lane & 15;
  const int bh = blockIdx.y;
  const int b = bh >> 4, h = bh & 15;
  const int q0 = blockIdx.x << 7;   // 128 q-rows per block

  short8 qhi[2][6], qlo[2][6];
  {
    const float scale = 0.07216878364870323f;  // 1/sqrt(192)
#pragma unroll
    for (int tl = 0; tl < 2; ++tl) {
      const int tok = b * N_ + q0 + wave * 32 + tl * 16 + lr;
      const float* qp = q_up + (size_t)tok * (H_ * QHD_) + h * QHD_;
#pragma unroll
      for (int c = 0; c < 6; ++c) {
        const float* src = qp + c * 32 + g * 8;
#pragma unroll
        for (int j = 0; j < 8; ++j) {
          short a, bq; bf_split(src[j] * scale, a, bq);
          qhi[tl][c][j] = a; qlo[tl][c][j] = bq;
        }
      }
    }
  }

  f32x4 acc_o[2][8];
#pragma unroll
  for (int tl = 0; tl < 2; ++tl)
#pragma unroll
    for (int i = 0; i < 8; ++i) acc_o[tl][i] = (f32x4){0.f, 0.f, 0.f, 0.f};
  float m_r[2][4], l_r[2][4];
#pragma unroll
  for (int tl = 0; tl < 2; ++tl)
#pragma unroll
    for (int j = 0; j < 4; ++j) { m_r[tl][j] = -1e30f; l_r[tl][j] = 0.f; }

  for (int kt = 0; kt < N_ / 32; ++kt) {
    __syncthreads();
    {
      const uint8_t* gkn = Kn + (((size_t)bh * 64 + kt) << 14);
      const uint8_t* gkp = Kp + (((size_t)b * 64 + kt) << 13);
      const uint8_t* gv  = Vv + (((size_t)bh * 64 + kt) << 14);
#pragma unroll
      for (int i = 0; i < 4; ++i)
        gload16(gkn + (wave * 4 + i) * 1024 + lane * 16, Ksn + (wave * 4 + i) * 1024);
#pragma unroll
      for (int i = 0; i < 2; ++i)
        gload16(gkp + (wave * 2 + i) * 1024 + lane * 16, Ksp + (wave * 2 + i) * 1024);
#pragma unroll
      for (int i = 0; i < 4; ++i)
        gload16(gv + (wave * 4 + i) * 1024 + lane * 16, Vs + (wave * 4 + i) * 1024);
    }
    __syncthreads();

    // ---- QK^T: per K-fragment read -> 6 MFMAs ----
    f32x4 accs[2][2];
#pragma unroll
    for (int t = 0; t < 2; ++t) {
      f32x4 aA = {0.f, 0.f, 0.f, 0.f};
      f32x4 aB = {0.f, 0.f, 0.f, 0.f};
      const int krow = t * 16 + lr;
      const int sw = (krow & 7) << 4;
      const uint8_t* kb = Ksn + krow * 512;
#pragma unroll
      for (int c = 0; c < 4; ++c) {
        short8 kh = *(const short8*)(kb + ((16 * (c * 4 + g)) ^ sw));
        short8 kl = *(const short8*)(kb + ((16 * (c * 4 + g + 16)) ^ sw));
        aA = __builtin_amdgcn_mfma_f32_16x16x32_bf16(qhi[0][c], kh, aA, 0, 0, 0);
        aA = __builtin_amdgcn_mfma_f32_16x16x32_bf16(qhi[0][c], kl, aA, 0, 0, 0);
        aA = __builtin_amdgcn_mfma_f32_16x16x32_bf16(qlo[0][c], kh, aA, 0, 0, 0);
        aB = __builtin_amdgcn_mfma_f32_16x16x32_bf16(qhi[1][c], kh, aB, 0, 0, 0);
        aB = __builtin_amdgcn_mfma_f32_16x16x32_bf16(qhi[1][c], kl, aB, 0, 0, 0);
        aB = __builtin_amdgcn_mfma_f32_16x16x32_bf16(qlo[1][c], kh, aB, 0, 0, 0);
      }
      const uint8_t* pb = Ksp + krow * 256;
#pragma unroll
      for (int c2 = 0; c2 < 2; ++c2) {
        short8 kh = *(const short8*)(pb + ((16 * (c2 * 4 + g)) ^ sw));
        short8 kl = *(const short8*)(pb + ((16 * (c2 * 4 + g + 8)) ^ sw));
        aA = __builtin_amdgcn_mfma_f32_16x16x32_bf16(qhi[0][4 + c2], kh, aA, 0, 0, 0);
        aA = __builtin_amdgcn_mfma_f32_16x16x32_bf16(qhi[0][4 + c2], kl, aA, 0, 0, 0);
        aA = __builtin_amdgcn_mfma_f32_16x16x32_bf16(qlo[0][4 + c2], kh, aA, 0, 0, 0);
        aB = __builtin_amdgcn_mfma_f32_16x16x32_bf16(qhi[1][4 + c2], kh, aB, 0, 0, 0);
        aB = __builtin_amdgcn_mfma_f32_16x16x32_bf16(qhi[1][4 + c2], kl, aB, 0, 0, 0);
        aB = __builtin_amdgcn_mfma_f32_16x16x32_bf16(qlo[1][4 + c2], kh, aB, 0, 0, 0);
      }
      accs[0][t] = aA; accs[1][t] = aB;
    }

    // ---- online softmax per tile (row = g*4+j lives in 16-lane group) ----
    float fac[2][4], p0[2][4], p1[2][4];
#pragma unroll
    for (int tl = 0; tl < 2; ++tl)
#pragma unroll
      for (int j = 0; j < 4; ++j) {
        float rm = fmaxf(accs[tl][0][j], accs[tl][1][j]);
        rm = fmaxf(rm, __shfl_xor(rm, 1, 64));
        rm = fmaxf(rm, __shfl_xor(rm, 2, 64));
        rm = fmaxf(rm, __shfl_xor(rm, 4, 64));
        rm = fmaxf(rm, __shfl_xor(rm, 8, 64));
        float mn = fmaxf(m_r[tl][j], rm);
        fac[tl][j] = __expf(m_r[tl][j] - mn);
        m_r[tl][j] = mn;
        p0[tl][j] = __expf(accs[tl][0][j] - mn);
        p1[tl][j] = __expf(accs[tl][1][j] - mn);
        float rs = p0[tl][j] + p1[tl][j];
        rs += __shfl_xor(rs, 1, 64);
        rs += __shfl_xor(rs, 2, 64);
        rs += __shfl_xor(rs, 4, 64);
        rs += __shfl_xor(rs, 8, 64);
        l_r[tl][j] = l_r[tl][j] * fac[tl][j] + rs;
      }
#pragma unroll
    for (int tl = 0; tl < 2; ++tl)
#pragma unroll
      for (int dt = 0; dt < 8; ++dt)
#pragma unroll
        for (int j = 0; j < 4; ++j) acc_o[tl][dt][j] *= fac[tl][j];

    // ---- P (hi/lo) -> per-wave swizzled LDS (transpose D->A layout) ----
#pragma unroll
    for (int tl = 0; tl < 2; ++tl) {
      uint8_t* pw = Ps + wave * 4096 + tl * 2048;
#pragma unroll
      for (int j = 0; j < 4; ++j) {
        int r = g * 4 + j;
        int rsw = (r & 7) << 4;
        uint8_t* rowp = pw + r * 128;
#pragma unroll
        for (int t = 0; t < 2; ++t) {
          float p = t ? p1[tl][j] : p0[tl][j];
          int k = t * 16 + lr;
          short a, bq; bf_split(p, a, bq);
          *(short*)(rowp + ((((k >> 3) + 0) * 16) ^ rsw) + (k & 7) * 2) = a;
          *(short*)(rowp + ((((k >> 3) + 4) * 16) ^ rsw) + (k & 7) * 2) = bq;
        }
      }
    }

    // ---- PV: per V-fragment read -> 6 MFMAs ----
    {
      const uint8_t* prA = Ps + wave * 4096 + lr * 128;
      const uint8_t* prB = prA + 2048;
      const int psw = (lr & 7) << 4;
      short8 phA = *(const short8*)(prA + ((16 * g) ^ psw));
      short8 plA = *(const short8*)(prA + ((16 * (4 + g)) ^ psw));
      short8 phB = *(const short8*)(prB + ((16 * g) ^ psw));
      short8 plB = *(const short8*)(prB + ((16 * (4 + g)) ^ psw));
#pragma unroll
      for (int dt = 0; dt < 8; ++dt) {
        int dcol = dt * 16 + lr;
        const uint8_t* vb = Vs + dcol * 128;
        int vsw = (dcol & 7) << 4;
        short8 vh = *(const short8*)(vb + ((16 * g) ^ vsw));
        short8 vl = *(const short8*)(vb + ((16 * (4 + g)) ^ vsw));
        acc_o[0][dt] = __builtin_amdgcn_mfma_f32_16x16x32_bf16(phA, vh, acc_o[0][dt], 0, 0, 0);
        acc_o[0][dt] = __builtin_amdgcn_mfma_f32_16x16x32_bf16(phA, vl, acc_o[0][dt], 0, 0, 0);
        acc_o[0][dt] = __builtin_amdgcn_mfma_f32_16x16x32_bf16(plA, vh, acc_o[0][dt], 0, 0, 0);
        acc_o[1][dt] = __builtin_amdgcn_mfma_f32_16x16x32_bf16(phB, vh, acc_o[1][dt], 0, 0, 0);
        acc_o[1][dt] = __builtin_amdgcn_mfma_f32_16x16x32_bf16(phB, vl, acc_o[1][dt], 0, 0, 0);
        acc_o[1][dt] = __builtin_amdgcn_mfma_f32_16x16x32_bf16(plB, vh, acc_o[1][dt], 0, 0, 0);
      }
    }
  }

  // ---- epilogue ----
#pragma unroll
  for (int tl = 0; tl < 2; ++tl) {
    float inv[4];
#pragma unroll
    for (int j = 0; j < 4; ++j) inv[j] = 1.f / l_r[tl][j];
    const int tokb = b * N_ + q0 + wave * 32 + tl * 16 + g * 4;
#pragma unroll
    for (int j = 0; j < 4; ++j) {
      float* orow = aout + (size_t)(tokb + j) * (H_ * DV_) + h * DV_;
#pragma unroll
      for (int dt = 0; dt < 8; ++dt)
        orow[dt * 16 + lr] = acc_o[tl][dt][j] * inv[j];
    }
  }
}

// ---------------------------------------------------------------------------
extern "C" void kernel_launch(void* const* d_in, const int* in_sizes, int n_in,
                              void* d_out, int out_size, void* d_ws, size_t ws_size,
                              hipStream_t stream) {
  (void)in_sizes; (void)n_in; (void)out_size; (void)ws_size;
  const float* x         = (const float*)d_in[0];
  const float* Wq_down   = (const float*)d_in[1];
  const float* q_norm_w  = (const float*)d_in[2];
  const float* Wq_up     = (const float*)d_in[3];
  const float* Wkv_down  = (const float*)d_in[4];
  const float* kv_norm_w = (const float*)d_in[5];
  const float* Wkv_up    = (const float*)d_in[6];
  const float* Wo        = (const float*)d_in[7];
  const int* pos_ids     = (const int*)d_in[9];
  float* out = (float*)d_out;

  // ws byte layout (peak ~167MB < 194MB proven):
  //  phase1: Xi[0,48M) Bslot[48M,76.5M) qtkv[76M..] q_up[110M..158M) kpe[158M..]
  //  phase2: kvA-img[64M,76M) WkvB-img[76M,88M) kv_up fp32 [0,64M)
  //  phase3: Kn[64M,96M)  V=d_out  a_out[0,32M)
  //  phase4: A2-img[32M,80M) Wo-img[96M,120M) -> out
  uint8_t* W = (uint8_t*)d_ws;
  uint8_t* Xi    = W;                          // 48MB x-image (also q-norm img 36MB)
  uint8_t* Bslot = W + 50331648;               // 28.3MB weight images
  float*   qtkv  = (float*)(W + 79691776);     // 4096 x 2176 fp32 (34MB)
  float*   q_up  = (float*)(W + 115343360);    // 4096 x 3072 fp32 (48MB)
  uint8_t* Kpimg = W + 165675008;              // 1MB
  uint8_t* KvAimg= W + 67108864;               // 12MB (kv rmsnorm image)
  uint8_t* WkvBimg=W + 79691776;               // 12MB (reuses dead qtkv)
  float*   kv_up = (float*)(W + 0);            // 64MB fp32 (reuses dead x/q images)
  uint8_t* Knimg = W + 67108864;               // 32MB
  float*   a_out = (float*)(W + 0);            // 32MB (reuses dead kv_up)
  uint8_t* A2img = W + 33554432;               // 48MB
  uint8_t* Woimg = W + 100663296;              // 24MB
  uint8_t* Vimg  = (uint8_t*)d_out;            // 32MB (dead before final GEMM)

  dim3 blk(256);
  // down-proj: x-img, [Wq_down | Wkv_down]-img, one GEMM (N = 1536+640pad)
  conv_a_kernel<<<4096, blk, 0, stream>>>(x, Xi, 2048, 96, 4096 * 256);
  conv_b_kernel<<<1536, blk, 0, stream>>>(Wq_down, Bslot, 2048, 1536, 1536, 0, 96, 1536 * 256);
  conv_b_kernel<<<640, blk, 0, stream>>>(Wkv_down, Bslot, 2048, 576, 640, 12, 96, 640 * 256);
  gemm_bf16_kernel<<<dim3(17, 32), blk, 0, stream>>>(Xi, Bslot, qtkv, 2176, 96);
  // q path
  rmsnorm_img_kernel<<<4096, blk, 0, stream>>>(qtkv, q_norm_w, Xi, 1536, 2176, 72);
  conv_b_kernel<<<2304, blk, 0, stream>>>(Wq_up, Bslot, 1536, 3072, 3072, 0, 72, 2304 * 256);
  gemm_bf16_kernel<<<dim3(24, 32), blk, 0, stream>>>(Xi, Bslot, q_up, 3072, 72);
  rope_q_kernel<<<256, blk, 0, stream>>>(q_up, pos_ids);
  // kv path (consume qtkv, then reuse its space)
  rope_k_kernel<<<16, blk, 0, stream>>>(qtkv, pos_ids, Kpimg);
  rmsnorm_img_kernel<<<4096, blk, 0, stream>>>(qtkv + 1536, kv_norm_w, KvAimg, 512, 2176, 24);
  conv_b_kernel<<<1024, blk, 0, stream>>>(Wkv_up, WkvBimg, 512, 4096, 4096, 0, 24, 1024 * 256);
  gemm_bf16_kernel<<<dim3(32, 32), blk, 0, stream>>>(KvAimg, WkvBimg, kv_up, 4096, 24);
  conv_kn_kernel<<<dim3(64, 32), blk, 0, stream>>>(kv_up, Knimg);
  conv_v_kernel<<<dim3(64, 32), blk, 0, stream>>>(kv_up, Vimg);
  // attention (128 q-rows per block)
  attn_mfma_kernel<<<dim3(16, 32), blk, 0, stream>>>(q_up, Knimg, Kpimg, Vimg, a_out);
  // output projection
  conv_a_kernel<<<4096, blk, 0, stream>>>(a_out, A2img, 2048, 96, 4096 * 256);
  conv_b_kernel<<<2048, blk, 0, stream>>>(Wo, Woimg, 2048, 2048, 2048, 0, 96, 2048 * 256);
  gemm_bf16_kernel<<<dim3(16, 32), blk, 0, stream>>>(A2img, Woimg, out, 2048, 96);
}